// Round 5
// baseline (175.203 us; speedup 1.0000x reference)
//
#include <hip/hip_runtime.h>

// DirectionalConv3d: B=8, C_IN=C_OUT=64, T=R=32, CO=32
// v6 design:
//  pass 1 (prep2): x fp32 [b][ch][s] -> bf16 [b][s][ch] in d_ws (+ bf16 weights).
//  pass 2 (conv6): software-pipelined 2-tile blocks.
//    - 512 thr = 8 waves: (sq 0..3) x (oh 0..1); wave = 64 s x 32 o, acc[4][2].
//    - ALL 28 B-frags preloaded to VGPRs in prologue (o-half split makes it fit)
//      -> compute phase has ZERO vmcnt waits (LDS taps are lgkm-only).
//    - 2 tiles/block, double-buffered 40KB LDS (80KB total, 2 blocks/CU):
//      stage(t1) + t1's t+-prefetch issued during t0 compute; single barrier
//      drain hidden behind ~2k cy of MFMA; t0 stores drain during t1 compute.
//    - A staged via async global_load_lds, source pre-swizzled (LDS dest linear).
// Tier 2 fallback: fused LDS kernel reading fp32 x (ws >= 56KB only).
// Tier 3 fallback: fp32 direct.

#define SB 32768   // spatial per batch (T*R*CO)
#define CIN 64
#define COUT 64
#define NB 8

typedef short s16x8 __attribute__((ext_vector_type(8)));
typedef __bf16 bf16x8 __attribute__((ext_vector_type(8)));
typedef float f32x4 __attribute__((ext_vector_type(4)));

__device__ __forceinline__ unsigned f2bf(float f) {
    unsigned u = __float_as_uint(f);
    u += 0x7FFFu + ((u >> 16) & 1u);   // round-to-nearest-even
    return u >> 16;
}
__device__ __forceinline__ unsigned pk2(float lo, float hi) {
    return f2bf(lo) | (f2bf(hi) << 16);
}

__device__ __forceinline__ void gload_lds16(const void* g, void* l) {
    __builtin_amdgcn_global_load_lds(
        (const __attribute__((address_space(1))) void*)g,
        (__attribute__((address_space(3))) void*)l, 16, 0, 0);
}

// ---------------- weight prep (tier-2 path): fp32 -> bf16, [tap][o][i] ----------------
__global__ __launch_bounds__(256) void wprep_kernel(const float* __restrict__ w0,
                            const float* __restrict__ w1, const float* __restrict__ w2,
                            const float* __restrict__ w3, const float* __restrict__ w4,
                            const float* __restrict__ w5, const float* __restrict__ w6,
                            unsigned short* __restrict__ ws) {
    int tap = blockIdx.x;
    int tid = threadIdx.x;
    const float* w = (tap == 0) ? w0 : (tap == 1) ? w1 : (tap == 2) ? w2
                   : (tap == 3) ? w3 : (tap == 4) ? w4 : (tap == 5) ? w5 : w6;
    unsigned p[8];
#pragma unroll
    for (int j = 0; j < 8; ++j)
        p[j] = pk2(w[tid * 16 + 2 * j], w[tid * 16 + 2 * j + 1]);
    uint4* dp = (uint4*)(ws + tap * 4096 + tid * 16);
    dp[0] = make_uint4(p[0], p[1], p[2], p[3]);
    dp[1] = make_uint4(p[4], p[5], p[6], p[7]);
}

// ---------------- pass 1: weights + x transpose/convert (LDS-free) ----------------
__global__ __launch_bounds__(256) void prep2_kernel(const float* __restrict__ x,
                            const float* __restrict__ w0, const float* __restrict__ w1,
                            const float* __restrict__ w2, const float* __restrict__ w3,
                            const float* __restrict__ w4, const float* __restrict__ w5,
                            const float* __restrict__ w6,
                            unsigned short* __restrict__ ws) {
    int bid = blockIdx.x;
    int tid = threadIdx.x;
    if (bid >= 4096) {                 // weight blocks
        int tap = bid - 4096;
        const float* w = (tap == 0) ? w0 : (tap == 1) ? w1 : (tap == 2) ? w2
                       : (tap == 3) ? w3 : (tap == 4) ? w4 : (tap == 5) ? w5 : w6;
        unsigned p[8];
#pragma unroll
        for (int j = 0; j < 8; ++j)
            p[j] = pk2(w[tid * 16 + 2 * j], w[tid * 16 + 2 * j + 1]);
        uint4* dp = (uint4*)(ws + tap * 4096 + tid * 16);
        dp[0] = make_uint4(p[0], p[1], p[2], p[3]);
        dp[1] = make_uint4(p[4], p[5], p[6], p[7]);
        return;
    }
    int lbid = ((bid & 7) << 9) | (bid >> 3);   // bijective: 4096 % 8 == 0
    int b = lbid >> 9;                          // batch = XCD
    int i = (lbid & 511) * 256 + tid;           // [0, 131072) per batch
    int cg = i & 7;                             // channel group (8 ch)
    int s = (i >> 3) * 2;                       // even spatial row
    const float* xb = x + (size_t)b * CIN * SB;
    unsigned short* xq = ws + 7 * 4096;
    unsigned pa[4], pb[4];
#pragma unroll
    for (int u = 0; u < 4; ++u) {
        int ch = cg * 8 + 2 * u;
        float2 v0 = *(const float2*)(xb + (size_t)ch * SB + s);
        float2 v1 = *(const float2*)(xb + (size_t)(ch + 1) * SB + s);
        pa[u] = pk2(v0.x, v1.x);
        pb[u] = pk2(v0.y, v1.y);
    }
    uint4* dst = (uint4*)(xq + ((size_t)b * SB + s) * 64 + cg * 8);
    dst[0] = make_uint4(pa[0], pa[1], pa[2], pa[3]);   // row s
    dst[8] = make_uint4(pb[0], pb[1], pb[2], pb[3]);   // row s+1 (+128B)
}

// ---------------- pass 2: pipelined 2-tile MFMA conv ----------------
// grid 512 = 8 b x 64 block-slices of 512 rows (2 tiles of 256).
// XCD-pinned: batch b = bid&7. 2 blocks/CU co-resident (80KB LDS each).
__global__ __launch_bounds__(512, 2) void conv6_kernel(const unsigned short* __restrict__ xq,
                                                       const unsigned short* __restrict__ wq,
                                                       float* __restrict__ out) {
    __shared__ uint4 alds[2][2560];   // 2 x 40KB double buffer, linear dest
    int bid = blockIdx.x;
    int b = bid & 7;                   // batch = XCD
    int l = bid >> 3;                  // 0..63
    int sblk0 = l << 9;                // tile0 base (512 rows per block)
    int sblk1 = sblk0 + 256;           // tile1 base
    int tid = threadIdx.x;
    int lane = tid & 63;
    int wv = tid >> 6;                 // 0..7
    int lo = lane & 15;
    int quad = lane >> 4;
    int oh = wv & 1;                   // o-half
    int sq = wv >> 1;                  // s-quarter (64 rows)
    const uint4* xch = (const uint4*)(xq + (size_t)b * (CIN * SB));

    // ---- B preload: all 28 frags (o-half) into VGPRs; zero in-loop B loads ----
    bf16x8 bq[7][2][2];
#pragma unroll
    for (int tap = 0; tap < 7; ++tap)
#pragma unroll
        for (int ks = 0; ks < 2; ++ks)
#pragma unroll
            for (int nt = 0; nt < 2; ++nt) {
                const unsigned short* bp = wq + tap * 4096
                    + (oh * 32 + nt * 16 + lo) * 64 + ks * 32 + quad * 8;
                bq[tap][ks][nt] = __builtin_bit_cast(bf16x8, *(const s16x8*)bp);
            }

    // tile-invariant LDS local rows
    int rl[4];
#pragma unroll
    for (int mt = 0; mt < 4; ++mt) rl[mt] = sq * 64 + mt * 16 + lo + 32;

    // stage one 320-row window via async DMA, source pre-swizzled
    auto stage = [&](int sblk, int bufidx) {
#pragma unroll
        for (int u = 0; u < 5; ++u) {
            int cid = u * 512 + tid;            // 0..2559
            int row = cid >> 3;
            int sc = cid & 7;
            int grow = sblk - 32 + row;
            grow = grow < 0 ? 0 : (grow > SB - 1 ? SB - 1 : grow);  // masked lanes only
            const uint4* g = xch + ((size_t)grow << 3) + (sc ^ (row & 7));
            gload_lds16((const void*)g, (void*)(&alds[bufidx][u * 512 + (wv << 6)]));
        }
    };
    // t+-1 A-frag prefetch into regs
    auto tgload = [&](int sblk, int d, uint4 (&tg)[8]) {
#pragma unroll
        for (int ks = 0; ks < 2; ++ks)
#pragma unroll
            for (int mt = 0; mt < 4; ++mt)
                tg[ks * 4 + mt] = xch[(size_t)(sblk + sq * 64 + mt * 16 + lo + d) * 8 + ks * 4 + quad];
    };

    const s16x8 zz = {0, 0, 0, 0, 0, 0, 0, 0};
    f32x4 acc[4][2];

    auto tap_reg = [&](const bf16x8 (&bt)[2][2], const uint4 (&tg)[8]) {
#pragma unroll
        for (int ks = 0; ks < 2; ++ks)
#pragma unroll
            for (int mt = 0; mt < 4; ++mt) {
                bf16x8 af = __builtin_bit_cast(bf16x8, tg[ks * 4 + mt]);
                acc[mt][0] = __builtin_amdgcn_mfma_f32_16x16x32_bf16(af, bt[ks][0], acc[mt][0], 0, 0, 0);
                acc[mt][1] = __builtin_amdgcn_mfma_f32_16x16x32_bf16(af, bt[ks][1], acc[mt][1], 0, 0, 0);
            }
    };
    auto tap_lds = [&](int bufidx, const bf16x8 (&bt)[2][2], int d, const bool (&ok)[4]) {
#pragma unroll
        for (int ks = 0; ks < 2; ++ks) {
            s16x8 a[4];
#pragma unroll
            for (int mt = 0; mt < 4; ++mt) {
                int row = rl[mt] + d;            // always in [0,320)
                a[mt] = *((const s16x8*)&alds[bufidx][0] + row * 8 + ((ks * 4 + quad) ^ (row & 7)));
            }
#pragma unroll
            for (int mt = 0; mt < 4; ++mt) {
                s16x8 raw = ok[mt] ? a[mt] : zz;
                bf16x8 af = __builtin_bit_cast(bf16x8, raw);
                acc[mt][0] = __builtin_amdgcn_mfma_f32_16x16x32_bf16(af, bt[ks][0], acc[mt][0], 0, 0, 0);
                acc[mt][1] = __builtin_amdgcn_mfma_f32_16x16x32_bf16(af, bt[ks][1], acc[mt][1], 0, 0, 0);
            }
        }
    };
    auto store_tile = [&](int sblk) {
#pragma unroll
        for (int mt = 0; mt < 4; ++mt)
#pragma unroll
            for (int nt = 0; nt < 2; ++nt) {
                int o = oh * 32 + nt * 16 + lo;
                size_t off = ((size_t)(b * COUT + o)) * SB + sblk + sq * 64 + mt * 16 + quad * 4;
                *(f32x4*)(out + off) = acc[mt][nt];
            }
    };

    int t0 = sblk0 >> 10, t1 = sblk1 >> 10;
    bool htm0 = (t0 > 0), htp0 = (t0 < 31);
    bool htm1 = (t1 > 0), htp1 = (t1 < 31);
    uint4 tgm[8], tgp[8];

    // ---- prologue: stage tile0 + tile0 t-prefetch ----
    stage(sblk0, 0);
    if (htm0) tgload(sblk0, -1024, tgm);
    if (htp0) tgload(sblk0, 1024, tgp);
    __syncthreads();                    // drains vmcnt(0): tile0 data ready

    // ================= tile 0 =================
#pragma unroll
    for (int mt = 0; mt < 4; ++mt)
#pragma unroll
        for (int nt = 0; nt < 2; ++nt) acc[mt][nt] = (f32x4){0.f, 0.f, 0.f, 0.f};

    stage(sblk1, 1);                    // async: tile1 staging in flight
    if (htm0) tap_reg(bq[1], tgm);      // consume tg0 (reg-only, no waits)
    if (htp0) tap_reg(bq[2], tgp);
    if (htm1) tgload(sblk1, -1024, tgm);  // refill tg for tile1 (after reads: safe WAR)
    if (htp1) tgload(sblk1, 1024, tgp);
    {
        int r_m[4], c_m[4];
#pragma unroll
        for (int mt = 0; mt < 4; ++mt) {
            int s = sblk0 + sq * 64 + mt * 16 + lo;
            r_m[mt] = (s >> 5) & 31;
            c_m[mt] = s & 31;
        }
        bool oka[4] = {true, true, true, true};
        tap_lds(0, bq[0], 0, oka);      // self  (lgkm-only from here)
        bool ok[4];
#pragma unroll
        for (int mt = 0; mt < 4; ++mt) ok[mt] = (r_m[mt] > 0);
        tap_lds(0, bq[3], -32, ok);     // r-1
#pragma unroll
        for (int mt = 0; mt < 4; ++mt) ok[mt] = (r_m[mt] < 31);
        tap_lds(0, bq[4], 32, ok);      // r+1
#pragma unroll
        for (int mt = 0; mt < 4; ++mt) ok[mt] = (c_m[mt] > 0);
        tap_lds(0, bq[5], -1, ok);      // c-1
#pragma unroll
        for (int mt = 0; mt < 4; ++mt) ok[mt] = (c_m[mt] < 31);
        tap_lds(0, bq[6], 1, ok);       // c+1
    }
    __syncthreads();                    // drains: tile1 stage + tg complete
    store_tile(sblk0);                  // fire-and-forget; drains during tile1

    // ================= tile 1 =================
#pragma unroll
    for (int mt = 0; mt < 4; ++mt)
#pragma unroll
        for (int nt = 0; nt < 2; ++nt) acc[mt][nt] = (f32x4){0.f, 0.f, 0.f, 0.f};

    if (htm1) tap_reg(bq[1], tgm);
    if (htp1) tap_reg(bq[2], tgp);
    {
        int r_m[4], c_m[4];
#pragma unroll
        for (int mt = 0; mt < 4; ++mt) {
            int s = sblk1 + sq * 64 + mt * 16 + lo;
            r_m[mt] = (s >> 5) & 31;
            c_m[mt] = s & 31;
        }
        bool oka[4] = {true, true, true, true};
        tap_lds(1, bq[0], 0, oka);
        bool ok[4];
#pragma unroll
        for (int mt = 0; mt < 4; ++mt) ok[mt] = (r_m[mt] > 0);
        tap_lds(1, bq[3], -32, ok);
#pragma unroll
        for (int mt = 0; mt < 4; ++mt) ok[mt] = (r_m[mt] < 31);
        tap_lds(1, bq[4], 32, ok);
#pragma unroll
        for (int mt = 0; mt < 4; ++mt) ok[mt] = (c_m[mt] > 0);
        tap_lds(1, bq[5], -1, ok);
#pragma unroll
        for (int mt = 0; mt < 4; ++mt) ok[mt] = (c_m[mt] < 31);
        tap_lds(1, bq[6], 1, ok);
    }
    store_tile(sblk1);
}

// ---------------- tier-2 fallback: fused LDS kernel on fp32 x ----------------
__global__ __launch_bounds__(256) void conv_kernel(const float* __restrict__ x,
                                                   const unsigned short* __restrict__ wq,
                                                   float* __restrict__ out) {
    __shared__ uint4 alds[2560];
    int bid = blockIdx.x;
    int b = bid >> 7;
    int sblk = (bid & 127) << 8;
    int tid = threadIdx.x;
    const float* xb = x + (size_t)b * CIN * SB;

    {
        int rl = 32 + tid;
        const float* xp = xb + sblk + tid;
#pragma unroll
        for (int c = 0; c < 4; ++c) {
            unsigned pk[8];
#pragma unroll
            for (int u = 0; u < 8; ++u)
                pk[u] = pk2(xp[(size_t)(c * 16 + 2 * u) * SB],
                            xp[(size_t)(c * 16 + 2 * u + 1) * SB]);
            alds[rl * 8 + ((2 * c) ^ (rl & 7))] = make_uint4(pk[0], pk[1], pk[2], pk[3]);
            alds[rl * 8 + ((2 * c + 1) ^ (rl & 7))] = make_uint4(pk[4], pk[5], pk[6], pk[7]);
        }
    }
    {
        int hrow = tid & 63;
        int rl = (hrow < 32) ? hrow : hrow + 256;
        int s = sblk - 32 + rl;
        s = max(0, min(SB - 1, s));
        int ic = tid >> 6;
        const float* xp = xb + s + (size_t)(ic * 16) * SB;
        unsigned pk[8];
#pragma unroll
        for (int u = 0; u < 8; ++u)
            pk[u] = pk2(xp[(size_t)(2 * u) * SB], xp[(size_t)(2 * u + 1) * SB]);
        alds[rl * 8 + ((2 * ic) ^ (rl & 7))] = make_uint4(pk[0], pk[1], pk[2], pk[3]);
        alds[rl * 8 + ((2 * ic + 1) ^ (rl & 7))] = make_uint4(pk[4], pk[5], pk[6], pk[7]);
    }
    __syncthreads();

    int lane = tid & 63;
    int wv = tid >> 6;
    int lo = lane & 15;
    int quad = lane >> 4;
    int sbase = sblk + wv * 64;
    int t = sblk >> 10;

    f32x4 acc[4][4];
#pragma unroll
    for (int mt = 0; mt < 4; ++mt)
#pragma unroll
        for (int nt = 0; nt < 4; ++nt)
            acc[mt][nt] = (f32x4){0.f, 0.f, 0.f, 0.f};

    int r_m[4], c_m[4], rl[4];
#pragma unroll
    for (int mt = 0; mt < 4; ++mt) {
        int s = sbase + mt * 16 + lo;
        r_m[mt] = (s >> 5) & 31;
        c_m[mt] = s & 31;
        rl[mt] = s - sblk + 32;
    }

    auto load_b = [&](const unsigned short* wt, int ks, int nt) -> bf16x8 {
        const unsigned short* bp = wt + (nt * 16 + lo) * 64 + ks * 32 + quad * 8;
        return __builtin_bit_cast(bf16x8, *(const s16x8*)bp);
    };

    auto run_tap_lds = [&](int tap, int d, const bool ok[4]) {
        const unsigned short* wt = wq + tap * 4096;
#pragma unroll
        for (int ks = 0; ks < 2; ++ks) {
            bf16x8 bf[4];
#pragma unroll
            for (int nt = 0; nt < 4; ++nt) bf[nt] = load_b(wt, ks, nt);
            int j = ks * 4 + quad;
#pragma unroll
            for (int mt = 0; mt < 4; ++mt) {
                int row = rl[mt] + d;
                s16x8 raw = *((const s16x8*)alds + row * 8 + (j ^ (row & 7)));
                s16x8 zx = {0, 0, 0, 0, 0, 0, 0, 0};
                raw = ok[mt] ? raw : zx;
                bf16x8 af = __builtin_bit_cast(bf16x8, raw);
#pragma unroll
                for (int nt = 0; nt < 4; ++nt)
                    acc[mt][nt] = __builtin_amdgcn_mfma_f32_16x16x32_bf16(af, bf[nt], acc[mt][nt], 0, 0, 0);
            }
        }
    };

    auto run_tap_gather = [&](int tap, int d) {
        const unsigned short* wt = wq + tap * 4096;
#pragma unroll
        for (int ks = 0; ks < 2; ++ks) {
            bf16x8 bf[4];
#pragma unroll
            for (int nt = 0; nt < 4; ++nt) bf[nt] = load_b(wt, ks, nt);
            const float* gp = xb + (size_t)(ks * 32 + quad * 8) * SB + d;
#pragma unroll
            for (int mt = 0; mt < 4; ++mt) {
                const float* ap = gp + sbase + mt * 16 + lo;
                unsigned pk[4];
#pragma unroll
                for (int u = 0; u < 4; ++u)
                    pk[u] = pk2(ap[(size_t)(2 * u) * SB], ap[(size_t)(2 * u + 1) * SB]);
                uint4 v = make_uint4(pk[0], pk[1], pk[2], pk[3]);
                bf16x8 af = __builtin_bit_cast(bf16x8, v);
#pragma unroll
                for (int nt = 0; nt < 4; ++nt)
                    acc[mt][nt] = __builtin_amdgcn_mfma_f32_16x16x32_bf16(af, bf[nt], acc[mt][nt], 0, 0, 0);
            }
        }
    };

    {
        bool ok_all[4] = {true, true, true, true};
        run_tap_lds(0, 0, ok_all);
    }
    if (t > 0)  run_tap_gather(1, -1024);
    if (t < 31) run_tap_gather(2, 1024);
    {
        bool ok[4];
#pragma unroll
        for (int mt = 0; mt < 4; ++mt) ok[mt] = (r_m[mt] > 0);
        run_tap_lds(3, -32, ok);
#pragma unroll
        for (int mt = 0; mt < 4; ++mt) ok[mt] = (r_m[mt] < 31);
        run_tap_lds(4, 32, ok);
#pragma unroll
        for (int mt = 0; mt < 4; ++mt) ok[mt] = (c_m[mt] > 0);
        run_tap_lds(5, -1, ok);
#pragma unroll
        for (int mt = 0; mt < 4; ++mt) ok[mt] = (c_m[mt] < 31);
        run_tap_lds(6, 1, ok);
    }

#pragma unroll
    for (int mt = 0; mt < 4; ++mt) {
#pragma unroll
        for (int nt = 0; nt < 4; ++nt) {
            int o = nt * 16 + lo;
            size_t off = ((size_t)(b * COUT + o)) * SB + sbase + mt * 16 + quad * 4;
            *(f32x4*)(out + off) = acc[mt][nt];
        }
    }
}

// ---------------- tier-3 fallback: fp32 direct ----------------
__global__ void fallback_kernel(const float* __restrict__ x,
                                const float* __restrict__ w0, const float* __restrict__ w1,
                                const float* __restrict__ w2, const float* __restrict__ w3,
                                const float* __restrict__ w4, const float* __restrict__ w5,
                                const float* __restrict__ w6,
                                float* __restrict__ out) {
    int bid = blockIdx.x;
    int b = bid >> 11;
    int og = (bid >> 7) & 15;
    int sblk = (bid & 127) << 8;
    int tid = threadIdx.x;
    __shared__ float wl[7][4][64];
    const float* wp[7] = {w0, w1, w2, w3, w4, w5, w6};
    for (int k = tid; k < 7 * 4 * 64; k += 256) {
        int tap = k >> 8, oo = (k >> 6) & 3, i = k & 63;
        wl[tap][oo][i] = wp[tap][(og * 4 + oo) * 64 + i];
    }
    __syncthreads();
    int s = sblk + tid;
    int t = s >> 10, r = (s >> 5) & 31, c = s & 31;
    const float* xb = x + (size_t)b * CIN * SB + s;
    float a0 = 0, a1 = 0, a2 = 0, a3 = 0;
    for (int i = 0; i < 64; ++i) {
        const float* xi = xb + (size_t)i * SB;
        float vs = xi[0];
        float vtp = (t > 0) ? xi[-1024] : 0.f;
        float vtm = (t < 31) ? xi[1024] : 0.f;
        float vrp = (r > 0) ? xi[-32] : 0.f;
        float vrm = (r < 31) ? xi[32] : 0.f;
        float vcp = (c > 0) ? xi[-1] : 0.f;
        float vcm = (c < 31) ? xi[1] : 0.f;
        a0 += wl[0][0][i] * vs + wl[1][0][i] * vtp + wl[2][0][i] * vtm + wl[3][0][i] * vrp + wl[4][0][i] * vrm + wl[5][0][i] * vcp + wl[6][0][i] * vcm;
        a1 += wl[0][1][i] * vs + wl[1][1][i] * vtp + wl[2][1][i] * vtm + wl[3][1][i] * vrp + wl[4][1][i] * vrm + wl[5][1][i] * vcp + wl[6][1][i] * vcm;
        a2 += wl[0][2][i] * vs + wl[1][2][i] * vtp + wl[2][2][i] * vtm + wl[3][2][i] * vrp + wl[4][2][i] * vrm + wl[5][2][i] * vcp + wl[6][2][i] * vcm;
        a3 += wl[0][3][i] * vs + wl[1][3][i] * vtp + wl[2][3][i] * vtm + wl[3][3][i] * vrp + wl[4][3][i] * vrm + wl[5][3][i] * vcp + wl[6][3][i] * vcm;
    }
    size_t obase = ((size_t)b * COUT + og * 4) * SB + s;
    out[obase] = a0;
    out[obase + SB] = a1;
    out[obase + 2 * (size_t)SB] = a2;
    out[obase + 3 * (size_t)SB] = a3;
}

extern "C" void kernel_launch(void* const* d_in, const int* in_sizes, int n_in,
                              void* d_out, int out_size, void* d_ws, size_t ws_size,
                              hipStream_t stream) {
    const float* x = (const float*)d_in[0];
    const float* w0 = (const float*)d_in[1];
    const float* w1 = (const float*)d_in[2];
    const float* w2 = (const float*)d_in[3];
    const float* w3 = (const float*)d_in[4];
    const float* w4 = (const float*)d_in[5];
    const float* w5 = (const float*)d_in[6];
    const float* w6 = (const float*)d_in[7];
    float* out = (float*)d_out;

    size_t need_w = (size_t)7 * 4096 * 2;                        // 56 KB weights
    size_t need_full = need_w + (size_t)NB * CIN * SB * 2;       // + 32 MB bf16 x
    if (d_ws != nullptr && ws_size >= need_full) {
        unsigned short* wsp = (unsigned short*)d_ws;
        prep2_kernel<<<4103, 256, 0, stream>>>(x, w0, w1, w2, w3, w4, w5, w6, wsp);
        conv6_kernel<<<512, 512, 0, stream>>>(wsp + 7 * 4096, wsp, out);
    } else if (d_ws != nullptr && ws_size >= need_w) {
        unsigned short* wsp = (unsigned short*)d_ws;
        wprep_kernel<<<7, 256, 0, stream>>>(w0, w1, w2, w3, w4, w5, w6, wsp);
        conv_kernel<<<1024, 256, 0, stream>>>(x, wsp, out);
    } else {
        fallback_kernel<<<8 * 16 * 128, 256, 0, stream>>>(x, w0, w1, w2, w3, w4, w5, w6, out);
    }
}